// Round 4
// baseline (242.763 us; speedup 1.0000x reference)
//
#include <hip/hip_runtime.h>

#define EMBED  1024
#define HEADS  16
#define DHEAD  64
#define SEQ    2048
#define BATCH  2
#define NTOK   4096
// softmax in exp2 domain: fold attention scale * log2(e) into Q pre-scale
#define QS2    (0.125f * 1.44269504089f)
#define DEFER_THR 8.0f

typedef unsigned short u16t;
typedef float f32x4 __attribute__((ext_vector_type(4)));
typedef __bf16 bf16x8 __attribute__((ext_vector_type(8)));
typedef u16t u16x8 __attribute__((ext_vector_type(8)));
typedef u16t u16x4 __attribute__((ext_vector_type(4)));
typedef unsigned u32x4 __attribute__((ext_vector_type(4)));

static __device__ __forceinline__ u16t f2bf(float f) {
    unsigned u = __builtin_bit_cast(unsigned, f);
    return (u16t)((u + 0x7fffu + ((u >> 16) & 1u)) >> 16);   // RNE
}
static __device__ __forceinline__ bf16x8 asbf(u16x8 v) {
    return __builtin_bit_cast(bf16x8, v);
}
static __device__ __forceinline__ f32x4 mfma16(bf16x8 a, bf16x8 b, f32x4 c) {
    return __builtin_amdgcn_mfma_f32_16x16x32_bf16(a, b, c, 0, 0, 0);
}
static __device__ __forceinline__ unsigned cvtpk(float lo, float hi) {
    unsigned r;
    asm("v_cvt_pk_bf16_f32 %0, %1, %2" : "=v"(r) : "v"(lo), "v"(hi));
    return r;
}

// async global->LDS, 16B per lane; LDS dest = uniform base + lane*16 (linear)
typedef const __attribute__((address_space(1))) void* as1cv;
typedef __attribute__((address_space(3))) void* as3v;
static __device__ __forceinline__ void ldsload16(const void* g, void* l) {
    __builtin_amdgcn_global_load_lds((as1cv)g, (as3v)l, 16, 0, 0);
}

// ---------- x fp32 -> bf16 ----------
__global__ __launch_bounds__(256)
void xcvt(const float* __restrict__ X, u16t* __restrict__ XB)
{
    const size_t i = ((size_t)blockIdx.x * 256 + threadIdx.x) * 8;
    float4 a = *(const float4*)&X[i];
    float4 b = *(const float4*)&X[i + 4];
    u16x8 o;
    o[0] = f2bf(a.x); o[1] = f2bf(a.y); o[2] = f2bf(a.z); o[3] = f2bf(a.w);
    o[4] = f2bf(b.x); o[5] = f2bf(b.y); o[6] = f2bf(b.z); o[7] = f2bf(b.w);
    *(u16x8*)&XB[i] = o;
}

// ---------- W [K][N] fp32 -> WT [N][K] bf16 (64x64 LDS tiles) ----------
__global__ __launch_bounds__(256)
void wtrans(const float* __restrict__ W, u16t* __restrict__ WT, int K, int N)
{
    __shared__ float L[64][65];
    const int t = threadIdx.x;
    const int k0 = blockIdx.y * 64, n0 = blockIdx.x * 64;
#pragma unroll
    for (int rep = 0; rep < 4; ++rep) {
        const int id = rep * 256 + t;
        const int kk = id >> 4, nc = (id & 15) * 4;
        float4 v = *(const float4*)&W[(size_t)(k0 + kk) * N + n0 + nc];
        L[kk][nc] = v.x; L[kk][nc + 1] = v.y; L[kk][nc + 2] = v.z; L[kk][nc + 3] = v.w;
    }
    __syncthreads();
#pragma unroll
    for (int rep = 0; rep < 2; ++rep) {
        const int id = rep * 256 + t;
        const int n = id >> 3, kc = (id & 7) * 8;
        u16x8 o;
#pragma unroll
        for (int i = 0; i < 8; ++i) o[i] = f2bf(L[kc + i][n]);
        *(u16x8*)&WT[(size_t)(n0 + n) * K + k0 + kc] = o;
    }
}

// ---------- V (b,h,s,d) bf16 -> Vt (b,h,d,s) bf16 ----------
__global__ __launch_bounds__(256)
void vtrans(const u16t* __restrict__ V, u16t* __restrict__ Vt)
{
    __shared__ u16t L[64][65];
    const int t = threadIdx.x;
    const int bh = blockIdx.y;
    const int s0 = blockIdx.x * 64;
    const u16t* src = V + ((size_t)bh * SEQ + s0) * DHEAD;
#pragma unroll
    for (int rep = 0; rep < 2; ++rep) {
        const int id = rep * 256 + t;
        const int s = id >> 3, dc = (id & 7) * 8;
        u16x8 v = *(const u16x8*)&src[(size_t)s * DHEAD + dc];
#pragma unroll
        for (int i = 0; i < 8; ++i) L[s][dc + i] = v[i];
    }
    __syncthreads();
    u16t* dstb = Vt + (size_t)bh * DHEAD * SEQ + s0;
#pragma unroll
    for (int rep = 0; rep < 2; ++rep) {
        const int id = rep * 256 + t;
        const int d = id >> 3, sc = (id & 7) * 8;
        u16x8 o;
#pragma unroll
        for (int i = 0; i < 8; ++i) o[i] = L[sc + i][d];
        *(u16x8*)&dstb[(size_t)d * SEQ + sc] = o;
    }
}

// ---------- bf16 GEMM (m97 structure): C = A[M,1024] @ WT[N,1024]^T + bias ----
// Linear [128][64] LDS tiles staged via global_load_lds_dwordx4.
// mode 0: fp32 out.  mode 1: QKV scatter -> bf16 Q(exp2-scaled)/K/V (b,h,s,d).
__global__ __launch_bounds__(256)
void gemm_bf16(const u16t* __restrict__ A, const u16t* __restrict__ BT,
               const float* __restrict__ bias, int N, int mode,
               float* __restrict__ C0, u16t* __restrict__ Qo,
               u16t* __restrict__ Ko, u16t* __restrict__ Vo)
{
    __shared__ __align__(16) u16t Al[128 * 64];
    __shared__ __align__(16) u16t Bl[128 * 64];
    const int t = threadIdx.x;
    const int lane = t & 63;
    const int g = lane >> 4, l15 = lane & 15;
    const int w = t >> 6, wr = w >> 1, wc = w & 1;
    const int m0 = blockIdx.y * 128, n0 = blockIdx.x * 128;

    // staging: wave w owns rows [w*32, w*32+32); lane i -> row +i/8, 16B chunk i%8
    const int srow = w * 32;            // wave-uniform
    const int lrow = lane >> 3;
    const int lcol = (lane & 7) * 8;    // u16 units

    f32x4 acc[4][4] = {};

    for (int k0 = 0; k0 < EMBED; k0 += 64) {
        __syncthreads();
#pragma unroll
        for (int r = 0; r < 4; ++r) {
            const int row = srow + r * 8;
            ldsload16(&A [(size_t)(m0 + row + lrow) * EMBED + k0 + lcol], &Al[row * 64]);
            ldsload16(&BT[(size_t)(n0 + row + lrow) * EMBED + k0 + lcol], &Bl[row * 64]);
        }
        __syncthreads();
#pragma unroll
        for (int kk = 0; kk < 2; ++kk) {
            bf16x8 av[4], bv[4];
#pragma unroll
            for (int i = 0; i < 4; ++i) {
                av[i] = asbf(*(const u16x8*)&Al[(wr * 64 + i * 16 + l15) * 64 + kk * 32 + g * 8]);
                bv[i] = asbf(*(const u16x8*)&Bl[(wc * 64 + i * 16 + l15) * 64 + kk * 32 + g * 8]);
            }
#pragma unroll
            for (int i = 0; i < 4; ++i)
#pragma unroll
                for (int j = 0; j < 4; ++j)
                    acc[i][j] = mfma16(av[i], bv[j], acc[i][j]);
        }
    }

#pragma unroll
    for (int i = 0; i < 4; ++i)
#pragma unroll
        for (int j = 0; j < 4; ++j)
#pragma unroll
            for (int r = 0; r < 4; ++r) {
                const int row = m0 + wr * 64 + i * 16 + g * 4 + r;
                const int col = n0 + wc * 64 + j * 16 + l15;
                float v = acc[i][j][r] + bias[col];
                if (mode == 0) {
                    C0[(size_t)row * N + col] = v;
                } else {
                    const int tt = col >> 10, c1 = col & 1023;
                    const int h = c1 >> 6, d = c1 & 63;
                    const int b = row >> 11, s = row & 2047;
                    if (tt == 0) v *= QS2;
                    u16t* dst = (tt == 0) ? Qo : (tt == 1 ? Ko : Vo);
                    dst[(((size_t)b * HEADS + h) * SEQ + s) * DHEAD + d] = f2bf(v);
                }
            }
}

// ---------- MFMA flash attention (exp2 domain, defer-max, cvt_pk) ----------
__global__ __launch_bounds__(256)
void attn_mfma(const u16t* __restrict__ Q, const u16t* __restrict__ K,
               const u16t* __restrict__ Vt, u16t* __restrict__ AO)
{
    __shared__ __align__(16) u16t Kl[64][72];   // [key][d]
    __shared__ __align__(16) u16t Vl[64][72];   // [d][key]
    const int t = threadIdx.x;
    const int lane = t & 63, wq = t >> 6;
    const int g = lane >> 4, l15 = lane & 15;
    const int bh = blockIdx.y;
    const int q0 = blockIdx.x * 64;
    const int b = bh >> 4, h = bh & 15;

    const u16t* qrow = Q + ((size_t)bh * SEQ + q0 + wq * 16 + l15) * DHEAD;
    bf16x8 qf[2];
    qf[0] = asbf(*(const u16x8*)&qrow[g * 8]);
    qf[1] = asbf(*(const u16x8*)&qrow[32 + g * 8]);

    const int srow = t >> 3, scol = (t & 7) * 8;
    const u16t* Kb = K + (size_t)bh * SEQ * DHEAD;
    const u16t* Vb = Vt + (size_t)bh * DHEAD * SEQ;

    f32x4 accO[4] = {};
    float mrun = -1e30f, lrun = 0.f;

    for (int kv0 = 0; kv0 < SEQ; kv0 += 64) {
        __syncthreads();
#pragma unroll
        for (int rep = 0; rep < 2; ++rep) {
            const int r = rep * 32 + srow;
            *(u16x8*)&Kl[r][scol] = *(const u16x8*)&Kb[(size_t)(kv0 + r) * DHEAD + scol];
            *(u16x8*)&Vl[r][scol] = *(const u16x8*)&Vb[(size_t)r * SEQ + kv0 + scol];
        }
        __syncthreads();

        f32x4 s4[4] = {};
#pragma unroll
        for (int kk = 0; kk < 2; ++kk)
#pragma unroll
            for (int mf = 0; mf < 4; ++mf) {
                bf16x8 a = asbf(*(const u16x8*)&Kl[mf * 16 + l15][kk * 32 + g * 8]);
                s4[mf] = mfma16(a, qf[kk], s4[mf]);
            }

        float mt = s4[0][0];
#pragma unroll
        for (int mf = 0; mf < 4; ++mf)
#pragma unroll
            for (int r = 0; r < 4; ++r) mt = fmaxf(mt, s4[mf][r]);
        mt = fmaxf(mt, __shfl_xor(mt, 16));
        mt = fmaxf(mt, __shfl_xor(mt, 32));

        // T13 defer-max: skip rescale while tile max stays within 2^THR of running max
        const bool skip = __all(mt - mrun <= DEFER_THR) != 0;
        const float mnew = skip ? mrun : fmaxf(mrun, mt);

        float p[4][4]; float rs = 0.f;
#pragma unroll
        for (int mf = 0; mf < 4; ++mf)
#pragma unroll
            for (int r = 0; r < 4; ++r) {
                p[mf][r] = __builtin_amdgcn_exp2f(s4[mf][r] - mnew);
                rs += p[mf][r];
            }
        rs += __shfl_xor(rs, 16);
        rs += __shfl_xor(rs, 32);

        if (skip) {
            lrun += rs;
        } else {
            const float alpha = __builtin_amdgcn_exp2f(mrun - mnew);
            lrun = lrun * alpha + rs;
            mrun = mnew;
            float al[4];
#pragma unroll
            for (int r = 0; r < 4; ++r) al[r] = __shfl(alpha, g * 4 + r);
#pragma unroll
            for (int nf = 0; nf < 4; ++nf)
#pragma unroll
                for (int r = 0; r < 4; ++r) accO[nf][r] *= al[r];
        }

        // P -> bf16 via v_cvt_pk_bf16_f32 (T12 primitive)
        u16x8 pu[2];
#pragma unroll
        for (int kk = 0; kk < 2; ++kk) {
            const int a = kk * 2;
            u32x4 pw;
            pw[0] = cvtpk(p[a][0], p[a][1]);
            pw[1] = cvtpk(p[a][2], p[a][3]);
            pw[2] = cvtpk(p[a + 1][0], p[a + 1][1]);
            pw[3] = cvtpk(p[a + 1][2], p[a + 1][3]);
            pu[kk] = __builtin_bit_cast(u16x8, pw);
        }

#pragma unroll
        for (int kk = 0; kk < 2; ++kk)
#pragma unroll
            for (int nf = 0; nf < 4; ++nf) {
                const u16t* vr = &Vl[nf * 16 + l15][0];
                u16x4 lo = *(const u16x4*)&vr[kk * 32 + g * 4];
                u16x4 hi = *(const u16x4*)&vr[kk * 32 + 16 + g * 4];
                u16x8 bb = __builtin_shufflevector(lo, hi, 0, 1, 2, 3, 4, 5, 6, 7);
                accO[nf] = mfma16(asbf(pu[kk]), asbf(bb), accO[nf]);
            }
    }

    const float inv = 1.f / lrun;
    float iv[4];
#pragma unroll
    for (int r = 0; r < 4; ++r) iv[r] = __shfl(inv, g * 4 + r);
#pragma unroll
    for (int nf = 0; nf < 4; ++nf)
#pragma unroll
        for (int r = 0; r < 4; ++r) {
            const int s = q0 + wq * 16 + g * 4 + r;
            AO[((size_t)b * SEQ + s) * EMBED + h * DHEAD + nf * 16 + l15] =
                f2bf(accO[nf][r] * iv[r]);
        }
}

// ---------- launch ----------
extern "C" void kernel_launch(void* const* d_in, const int* in_sizes, int n_in,
                              void* d_out, int out_size, void* d_ws, size_t ws_size,
                              hipStream_t stream)
{
    const float* x     = (const float*)d_in[0];
    const float* w_qkv = (const float*)d_in[1];
    const float* b_qkv = (const float*)d_in[2];
    const float* w_out = (const float*)d_in[3];
    const float* b_out = (const float*)d_in[4];

    u16t* xb  = (u16t*)d_ws;
    u16t* wqt = xb  + (size_t)NTOK * EMBED;
    u16t* wot = wqt + (size_t)3072 * 1024;
    u16t* Qb  = wot + (size_t)1024 * 1024;
    u16t* Kb  = Qb  + (size_t)NTOK * EMBED;
    u16t* Vb  = Kb  + (size_t)NTOK * EMBED;
    u16t* Vtb = Vb  + (size_t)NTOK * EMBED;
    u16t* AOb = Vtb + (size_t)NTOK * EMBED;

    xcvt<<<2048, 256, 0, stream>>>(x, xb);
    wtrans<<<dim3(48, 16), 256, 0, stream>>>(w_qkv, wqt, 1024, 3072);
    wtrans<<<dim3(16, 16), 256, 0, stream>>>(w_out, wot, 1024, 1024);

    gemm_bf16<<<dim3(24, 32), 256, 0, stream>>>(xb, wqt, b_qkv, 3072, 1,
                                                nullptr, Qb, Kb, Vb);
    vtrans<<<dim3(32, 32), 256, 0, stream>>>(Vb, Vtb);
    attn_mfma<<<dim3(32, 32), 256, 0, stream>>>(Qb, Kb, Vtb, AOb);
    gemm_bf16<<<dim3(8, 32), 256, 0, stream>>>(AOb, wot, b_out, 1024, 0,
                                               (float*)d_out, nullptr, nullptr, nullptr);
}

// Round 5
// 241.675 us; speedup vs baseline: 1.0045x; 1.0045x over previous
//
#include <hip/hip_runtime.h>

#define EMBED  1024
#define HEADS  16
#define DHEAD  64
#define SEQ    2048
#define BATCH  2
#define NTOK   4096
// softmax in exp2 domain: fold attention scale * log2(e) into Q pre-scale
#define QS2    (0.125f * 1.44269504089f)
#define DEFER_THR 8.0f

typedef unsigned short u16t;
typedef float f32x4 __attribute__((ext_vector_type(4)));
typedef __bf16 bf16x8 __attribute__((ext_vector_type(8)));
typedef u16t u16x8 __attribute__((ext_vector_type(8)));
typedef u16t u16x4 __attribute__((ext_vector_type(4)));
typedef unsigned u32x4 __attribute__((ext_vector_type(4)));

static __device__ __forceinline__ u16t f2bf(float f) {
    unsigned u = __builtin_bit_cast(unsigned, f);
    return (u16t)((u + 0x7fffu + ((u >> 16) & 1u)) >> 16);   // RNE
}
static __device__ __forceinline__ bf16x8 asbf(u16x8 v) {
    return __builtin_bit_cast(bf16x8, v);
}
static __device__ __forceinline__ f32x4 mfma16(bf16x8 a, bf16x8 b, f32x4 c) {
    return __builtin_amdgcn_mfma_f32_16x16x32_bf16(a, b, c, 0, 0, 0);
}
static __device__ __forceinline__ unsigned cvtpk(float lo, float hi) {
    unsigned r;
    asm("v_cvt_pk_bf16_f32 %0, %1, %2" : "=v"(r) : "v"(lo), "v"(hi));
    return r;
}

// async global->LDS, 16B per lane; LDS dest = uniform base + lane*16 (linear)
typedef const __attribute__((address_space(1))) void* as1cv;
typedef __attribute__((address_space(3))) void* as3v;
static __device__ __forceinline__ void ldsload16(const void* g, void* l) {
    __builtin_amdgcn_global_load_lds((as1cv)g, (as3v)l, 16, 0, 0);
}

// ---------- x fp32 -> bf16 ----------
__global__ __launch_bounds__(256)
void xcvt(const float* __restrict__ X, u16t* __restrict__ XB)
{
    const size_t i = ((size_t)blockIdx.x * 256 + threadIdx.x) * 8;
    float4 a = *(const float4*)&X[i];
    float4 b = *(const float4*)&X[i + 4];
    u16x8 o;
    o[0] = f2bf(a.x); o[1] = f2bf(a.y); o[2] = f2bf(a.z); o[3] = f2bf(a.w);
    o[4] = f2bf(b.x); o[5] = f2bf(b.y); o[6] = f2bf(b.z); o[7] = f2bf(b.w);
    *(u16x8*)&XB[i] = o;
}

// ---------- W [K][N] fp32 -> WT [N][K] bf16 (64x64 LDS tiles) ----------
__global__ __launch_bounds__(256)
void wtrans(const float* __restrict__ W, u16t* __restrict__ WT, int K, int N)
{
    __shared__ float L[64][65];
    const int t = threadIdx.x;
    const int k0 = blockIdx.y * 64, n0 = blockIdx.x * 64;
#pragma unroll
    for (int rep = 0; rep < 4; ++rep) {
        const int id = rep * 256 + t;
        const int kk = id >> 4, nc = (id & 15) * 4;
        float4 v = *(const float4*)&W[(size_t)(k0 + kk) * N + n0 + nc];
        L[kk][nc] = v.x; L[kk][nc + 1] = v.y; L[kk][nc + 2] = v.z; L[kk][nc + 3] = v.w;
    }
    __syncthreads();
#pragma unroll
    for (int rep = 0; rep < 2; ++rep) {
        const int id = rep * 256 + t;
        const int n = id >> 3, kc = (id & 7) * 8;
        u16x8 o;
#pragma unroll
        for (int i = 0; i < 8; ++i) o[i] = f2bf(L[kc + i][n]);
        *(u16x8*)&WT[(size_t)(n0 + n) * K + k0 + kc] = o;
    }
}

// ---------- V (b,h,s,d) bf16 -> Vt (b,h,d,s) bf16 ----------
__global__ __launch_bounds__(256)
void vtrans(const u16t* __restrict__ V, u16t* __restrict__ Vt)
{
    __shared__ u16t L[64][65];
    const int t = threadIdx.x;
    const int bh = blockIdx.y;
    const int s0 = blockIdx.x * 64;
    const u16t* src = V + ((size_t)bh * SEQ + s0) * DHEAD;
#pragma unroll
    for (int rep = 0; rep < 2; ++rep) {
        const int id = rep * 256 + t;
        const int s = id >> 3, dc = (id & 7) * 8;
        u16x8 v = *(const u16x8*)&src[(size_t)s * DHEAD + dc];
#pragma unroll
        for (int i = 0; i < 8; ++i) L[s][dc + i] = v[i];
    }
    __syncthreads();
    u16t* dstb = Vt + (size_t)bh * DHEAD * SEQ + s0;
#pragma unroll
    for (int rep = 0; rep < 2; ++rep) {
        const int id = rep * 256 + t;
        const int d = id >> 3, sc = (id & 7) * 8;
        u16x8 o;
#pragma unroll
        for (int i = 0; i < 8; ++i) o[i] = L[sc + i][d];
        *(u16x8*)&dstb[(size_t)d * SEQ + sc] = o;
    }
}

// ---------- bf16 GEMM, T3-minimum 2-phase double-buffered ----------
// C = A[M,1024] @ WT[N,1024]^T + bias; stage(t+1) issued before compute(t),
// one barrier per K-step (its implicit vmcnt/lgkm drain is the fence).
__global__ __launch_bounds__(256)
void gemm_bf16(const u16t* __restrict__ A, const u16t* __restrict__ BT,
               const float* __restrict__ bias, int N, int mode,
               float* __restrict__ C0, u16t* __restrict__ Qo,
               u16t* __restrict__ Ko, u16t* __restrict__ Vo)
{
    __shared__ __align__(16) u16t Al[2][128 * 64];
    __shared__ __align__(16) u16t Bl[2][128 * 64];
    const int t = threadIdx.x;
    const int lane = t & 63;
    const int g = lane >> 4, l15 = lane & 15;
    const int w = t >> 6, wr = w >> 1, wc = w & 1;
    const int m0 = blockIdx.y * 128, n0 = blockIdx.x * 128;

    // staging: wave w owns rows [w*32, w*32+32); lane -> row +lane/8, chunk lane%8
    const int srow = w * 32;            // wave-uniform
    const int lrow = lane >> 3;
    const int lcol = (lane & 7) * 8;    // u16 units

#define GSTAGE(buf, k0)                                                          \
    {                                                                            \
        _Pragma("unroll")                                                        \
        for (int r_ = 0; r_ < 4; ++r_) {                                         \
            const int row_ = srow + r_ * 8;                                      \
            ldsload16(&A [(size_t)(m0 + row_ + lrow) * EMBED + (k0) + lcol],     \
                      &Al[buf][row_ * 64]);                                      \
            ldsload16(&BT[(size_t)(n0 + row_ + lrow) * EMBED + (k0) + lcol],     \
                      &Bl[buf][row_ * 64]);                                      \
        }                                                                        \
    }

    f32x4 acc[4][4] = {};

    GSTAGE(0, 0);
    __syncthreads();                    // drains vmcnt -> tile 0 in LDS

    int cur = 0;
    for (int k0 = 0; k0 < EMBED; k0 += 64) {
        if (k0 + 64 < EMBED) GSTAGE(cur ^ 1, k0 + 64);   // prefetch next tile
        const u16t* Ab = &Al[cur][0];
        const u16t* Bb = &Bl[cur][0];
#pragma unroll
        for (int kk = 0; kk < 2; ++kk) {
            bf16x8 av[4], bv[4];
#pragma unroll
            for (int i = 0; i < 4; ++i) {
                av[i] = asbf(*(const u16x8*)&Ab[(wr * 64 + i * 16 + l15) * 64 + kk * 32 + g * 8]);
                bv[i] = asbf(*(const u16x8*)&Bb[(wc * 64 + i * 16 + l15) * 64 + kk * 32 + g * 8]);
            }
#pragma unroll
            for (int i = 0; i < 4; ++i)
#pragma unroll
                for (int j = 0; j < 4; ++j)
                    acc[i][j] = mfma16(av[i], bv[j], acc[i][j]);
        }
        __syncthreads();                // drains vmcnt(0): next tile ready
        cur ^= 1;
    }
#undef GSTAGE

#pragma unroll
    for (int i = 0; i < 4; ++i)
#pragma unroll
        for (int j = 0; j < 4; ++j)
#pragma unroll
            for (int r = 0; r < 4; ++r) {
                const int row = m0 + wr * 64 + i * 16 + g * 4 + r;
                const int col = n0 + wc * 64 + j * 16 + l15;
                float v = acc[i][j][r] + bias[col];
                if (mode == 0) {
                    C0[(size_t)row * N + col] = v;
                } else {
                    const int tt = col >> 10, c1 = col & 1023;
                    const int h = c1 >> 6, d = c1 & 63;
                    const int b = row >> 11, s = row & 2047;
                    if (tt == 0) v *= QS2;
                    u16t* dst = (tt == 0) ? Qo : (tt == 1 ? Ko : Vo);
                    dst[(((size_t)b * HEADS + h) * SEQ + s) * DHEAD + d] = f2bf(v);
                }
            }
}

// ---------- MFMA flash attention: QBLK=128, T14 early-issue staging ----------
// 4 waves x 32 q. K fragments and V fragments each feed 2 MFMAs (qh=0,1).
__global__ __launch_bounds__(256)
void attn_mfma(const u16t* __restrict__ Q, const u16t* __restrict__ K,
               const u16t* __restrict__ Vt, u16t* __restrict__ AO)
{
    __shared__ __align__(16) u16t Kl[64][72];   // [key][d], padded
    __shared__ __align__(16) u16t Vl[64][72];   // [d][key], padded
    const int t = threadIdx.x;
    const int lane = t & 63, wq = t >> 6;
    const int g = lane >> 4, l15 = lane & 15;
    const int bh = blockIdx.y;
    const int q0 = blockIdx.x * 128;
    const int b = bh >> 4, h = bh & 15;

    // Q fragments: 32 q-rows per wave (two 16-row groups)
    const u16t* qbase = Q + ((size_t)bh * SEQ + q0 + wq * 32) * DHEAD;
    bf16x8 qf[2][2];
#pragma unroll
    for (int qh = 0; qh < 2; ++qh)
#pragma unroll
        for (int kk = 0; kk < 2; ++kk)
            qf[qh][kk] = asbf(*(const u16x8*)&qbase[(size_t)(qh * 16 + l15) * DHEAD + kk * 32 + g * 8]);

    const int srow = t >> 3, scol = (t & 7) * 8;
    const u16t* Kb = K + (size_t)bh * SEQ * DHEAD;
    const u16t* Vb = Vt + (size_t)bh * DHEAD * SEQ;

    // prologue: stage tile 0
    {
        u16x8 k0r[2], v0r[2];
#pragma unroll
        for (int rep = 0; rep < 2; ++rep) {
            const int r = rep * 32 + srow;
            k0r[rep] = *(const u16x8*)&Kb[(size_t)r * DHEAD + scol];
            v0r[rep] = *(const u16x8*)&Vb[(size_t)r * SEQ + scol];
        }
#pragma unroll
        for (int rep = 0; rep < 2; ++rep) {
            const int r = rep * 32 + srow;
            *(u16x8*)&Kl[r][scol] = k0r[rep];
            *(u16x8*)&Vl[r][scol] = v0r[rep];
        }
    }
    __syncthreads();

    f32x4 accO[4][2] = {};
    float mrun[2] = {-1e30f, -1e30f}, lrun[2] = {0.f, 0.f};

    for (int kv0 = 0; kv0 < SEQ; kv0 += 64) {
        const bool more = (kv0 + 64 < SEQ);
        // T14: issue next tile's global loads now; write to LDS after barrier
        u16x8 kreg[2], vreg[2];
        if (more) {
#pragma unroll
            for (int rep = 0; rep < 2; ++rep) {
                const int r = rep * 32 + srow;
                kreg[rep] = *(const u16x8*)&Kb[(size_t)(kv0 + 64 + r) * DHEAD + scol];
                vreg[rep] = *(const u16x8*)&Vb[(size_t)r * SEQ + kv0 + 64 + scol];
            }
        }

        // ---- QK^T: S^T[key][q] for both q-halves ----
        f32x4 s4[4][2] = {};
#pragma unroll
        for (int kk = 0; kk < 2; ++kk)
#pragma unroll
            for (int mf = 0; mf < 4; ++mf) {
                bf16x8 a = asbf(*(const u16x8*)&Kl[mf * 16 + l15][kk * 32 + g * 8]);
                s4[mf][0] = mfma16(a, qf[0][kk], s4[mf][0]);
                s4[mf][1] = mfma16(a, qf[1][kk], s4[mf][1]);
            }

        // ---- online softmax (exp2 domain, defer-max) ----
        float mt[2];
#pragma unroll
        for (int qh = 0; qh < 2; ++qh) {
            float m = s4[0][qh][0];
#pragma unroll
            for (int mf = 0; mf < 4; ++mf)
#pragma unroll
                for (int r = 0; r < 4; ++r) m = fmaxf(m, s4[mf][qh][r]);
            m = fmaxf(m, __shfl_xor(m, 16));
            m = fmaxf(m, __shfl_xor(m, 32));
            mt[qh] = m;
        }
        const bool skip =
            __all((mt[0] - mrun[0] <= DEFER_THR) && (mt[1] - mrun[1] <= DEFER_THR)) != 0;
        float mnew[2];
#pragma unroll
        for (int qh = 0; qh < 2; ++qh)
            mnew[qh] = skip ? mrun[qh] : fmaxf(mrun[qh], mt[qh]);

        float p[4][2][4], rs[2] = {0.f, 0.f};
#pragma unroll
        for (int mf = 0; mf < 4; ++mf)
#pragma unroll
            for (int qh = 0; qh < 2; ++qh)
#pragma unroll
                for (int r = 0; r < 4; ++r) {
                    p[mf][qh][r] = __builtin_amdgcn_exp2f(s4[mf][qh][r] - mnew[qh]);
                    rs[qh] += p[mf][qh][r];
                }
#pragma unroll
        for (int qh = 0; qh < 2; ++qh) {
            rs[qh] += __shfl_xor(rs[qh], 16);
            rs[qh] += __shfl_xor(rs[qh], 32);
        }

        if (skip) {
            lrun[0] += rs[0];
            lrun[1] += rs[1];
        } else {
#pragma unroll
            for (int qh = 0; qh < 2; ++qh) {
                const float alpha = __builtin_amdgcn_exp2f(mrun[qh] - mnew[qh]);
                lrun[qh] = lrun[qh] * alpha + rs[qh];
                mrun[qh] = mnew[qh];
                float al[4];
#pragma unroll
                for (int r = 0; r < 4; ++r) al[r] = __shfl(alpha, g * 4 + r);
#pragma unroll
                for (int nf = 0; nf < 4; ++nf)
#pragma unroll
                    for (int r = 0; r < 4; ++r) accO[nf][qh][r] *= al[r];
            }
        }

        // ---- P -> bf16 (cvt_pk), k-permuted A-fragments ----
        u16x8 pu[2][2];
#pragma unroll
        for (int kk = 0; kk < 2; ++kk)
#pragma unroll
            for (int qh = 0; qh < 2; ++qh) {
                const int a = kk * 2;
                u32x4 pw;
                pw[0] = cvtpk(p[a][qh][0], p[a][qh][1]);
                pw[1] = cvtpk(p[a][qh][2], p[a][qh][3]);
                pw[2] = cvtpk(p[a + 1][qh][0], p[a + 1][qh][1]);
                pw[3] = cvtpk(p[a + 1][qh][2], p[a + 1][qh][3]);
                pu[kk][qh] = __builtin_bit_cast(u16x8, pw);
            }

        // ---- PV: V fragment shared across q-halves ----
#pragma unroll
        for (int kk = 0; kk < 2; ++kk)
#pragma unroll
            for (int nf = 0; nf < 4; ++nf) {
                const u16t* vr = &Vl[nf * 16 + l15][0];
                u16x4 lo = *(const u16x4*)&vr[kk * 32 + g * 4];
                u16x4 hi = *(const u16x4*)&vr[kk * 32 + 16 + g * 4];
                u16x8 bb = __builtin_shufflevector(lo, hi, 0, 1, 2, 3, 4, 5, 6, 7);
                accO[nf][0] = mfma16(asbf(pu[kk][0]), asbf(bb), accO[nf][0]);
                accO[nf][1] = mfma16(asbf(pu[kk][1]), asbf(bb), accO[nf][1]);
            }

        __syncthreads();                // all waves done reading Kl/Vl
        if (more) {
#pragma unroll
            for (int rep = 0; rep < 2; ++rep) {
                const int r = rep * 32 + srow;
                *(u16x8*)&Kl[r][scol] = kreg[rep];
                *(u16x8*)&Vl[r][scol] = vreg[rep];
            }
            __syncthreads();            // next tile ready
        }
    }

#pragma unroll
    for (int qh = 0; qh < 2; ++qh) {
        const float inv = 1.f / lrun[qh];
        float iv[4];
#pragma unroll
        for (int r = 0; r < 4; ++r) iv[r] = __shfl(inv, g * 4 + r);
#pragma unroll
        for (int nf = 0; nf < 4; ++nf)
#pragma unroll
            for (int r = 0; r < 4; ++r) {
                const int s = q0 + wq * 32 + qh * 16 + g * 4 + r;
                AO[((size_t)b * SEQ + s) * EMBED + h * DHEAD + nf * 16 + l15] =
                    f2bf(accO[nf][qh][r] * iv[r]);
            }
    }
}

// ---------- launch ----------
extern "C" void kernel_launch(void* const* d_in, const int* in_sizes, int n_in,
                              void* d_out, int out_size, void* d_ws, size_t ws_size,
                              hipStream_t stream)
{
    const float* x     = (const float*)d_in[0];
    const float* w_qkv = (const float*)d_in[1];
    const float* b_qkv = (const float*)d_in[2];
    const float* w_out = (const float*)d_in[3];
    const float* b_out = (const float*)d_in[4];

    u16t* xb  = (u16t*)d_ws;
    u16t* wqt = xb  + (size_t)NTOK * EMBED;
    u16t* wot = wqt + (size_t)3072 * 1024;
    u16t* Qb  = wot + (size_t)1024 * 1024;
    u16t* Kb  = Qb  + (size_t)NTOK * EMBED;
    u16t* Vb  = Kb  + (size_t)NTOK * EMBED;
    u16t* Vtb = Vb  + (size_t)NTOK * EMBED;
    u16t* AOb = Vtb + (size_t)NTOK * EMBED;

    xcvt<<<2048, 256, 0, stream>>>(x, xb);
    wtrans<<<dim3(48, 16), 256, 0, stream>>>(w_qkv, wqt, 1024, 3072);
    wtrans<<<dim3(16, 16), 256, 0, stream>>>(w_out, wot, 1024, 1024);

    gemm_bf16<<<dim3(24, 32), 256, 0, stream>>>(xb, wqt, b_qkv, 3072, 1,
                                                nullptr, Qb, Kb, Vb);
    vtrans<<<dim3(32, 32), 256, 0, stream>>>(Vb, Vtb);
    attn_mfma<<<dim3(16, 32), 256, 0, stream>>>(Qb, Kb, Vtb, AOb);
    gemm_bf16<<<dim3(8, 32), 256, 0, stream>>>(AOb, wot, b_out, 1024, 0,
                                               (float*)d_out, nullptr, nullptr, nullptr);
}

// Round 6
// 225.304 us; speedup vs baseline: 1.0775x; 1.0727x over previous
//
#include <hip/hip_runtime.h>

#define EMBED  1024
#define HEADS  16
#define DHEAD  64
#define SEQ    2048
#define BATCH  2
#define NTOK   4096
// softmax in exp2 domain: fold attention scale * log2(e) into Q pre-scale
#define QS2    (0.125f * 1.44269504089f)
#define DEFER_THR 8.0f

typedef unsigned short u16t;
typedef float f32x4 __attribute__((ext_vector_type(4)));
typedef __bf16 bf16x8 __attribute__((ext_vector_type(8)));
typedef u16t u16x8 __attribute__((ext_vector_type(8)));
typedef u16t u16x4 __attribute__((ext_vector_type(4)));
typedef unsigned u32x4 __attribute__((ext_vector_type(4)));

static __device__ __forceinline__ u16t f2bf(float f) {
    unsigned u = __builtin_bit_cast(unsigned, f);
    return (u16t)((u + 0x7fffu + ((u >> 16) & 1u)) >> 16);   // RNE
}
static __device__ __forceinline__ bf16x8 asbf(u16x8 v) {
    return __builtin_bit_cast(bf16x8, v);
}
static __device__ __forceinline__ f32x4 mfma16(bf16x8 a, bf16x8 b, f32x4 c) {
    return __builtin_amdgcn_mfma_f32_16x16x32_bf16(a, b, c, 0, 0, 0);
}
static __device__ __forceinline__ unsigned cvtpk(float lo, float hi) {
    unsigned r;
    asm("v_cvt_pk_bf16_f32 %0, %1, %2" : "=v"(r) : "v"(lo), "v"(hi));
    return r;
}

// async global->LDS, 16B per lane; LDS dest = uniform base + lane*16 (linear)
typedef const __attribute__((address_space(1))) void* as1cv;
typedef __attribute__((address_space(3))) void* as3v;
static __device__ __forceinline__ void ldsload16(const void* g, void* l) {
    __builtin_amdgcn_global_load_lds((as1cv)g, (as3v)l, 16, 0, 0);
}

// ---------- x fp32 -> bf16 ----------
__global__ __launch_bounds__(256)
void xcvt(const float* __restrict__ X, u16t* __restrict__ XB)
{
    const size_t i = ((size_t)blockIdx.x * 256 + threadIdx.x) * 8;
    float4 a = *(const float4*)&X[i];
    float4 b = *(const float4*)&X[i + 4];
    u16x8 o;
    o[0] = f2bf(a.x); o[1] = f2bf(a.y); o[2] = f2bf(a.z); o[3] = f2bf(a.w);
    o[4] = f2bf(b.x); o[5] = f2bf(b.y); o[6] = f2bf(b.z); o[7] = f2bf(b.w);
    *(u16x8*)&XB[i] = o;
}

// ---------- W [K][N] fp32 -> WT [N][K] bf16 (64x64 LDS tiles) ----------
__global__ __launch_bounds__(256)
void wtrans(const float* __restrict__ W, u16t* __restrict__ WT, int K, int N)
{
    __shared__ float L[64][65];
    const int t = threadIdx.x;
    const int k0 = blockIdx.y * 64, n0 = blockIdx.x * 64;
#pragma unroll
    for (int rep = 0; rep < 4; ++rep) {
        const int id = rep * 256 + t;
        const int kk = id >> 4, nc = (id & 15) * 4;
        float4 v = *(const float4*)&W[(size_t)(k0 + kk) * N + n0 + nc];
        L[kk][nc] = v.x; L[kk][nc + 1] = v.y; L[kk][nc + 2] = v.z; L[kk][nc + 3] = v.w;
    }
    __syncthreads();
#pragma unroll
    for (int rep = 0; rep < 2; ++rep) {
        const int id = rep * 256 + t;
        const int n = id >> 3, kc = (id & 7) * 8;
        u16x8 o;
#pragma unroll
        for (int i = 0; i < 8; ++i) o[i] = f2bf(L[kc + i][n]);
        *(u16x8*)&WT[(size_t)(n0 + n) * K + k0 + kc] = o;
    }
}

// ---------- V (b,h,s,d) bf16 -> Vt (b,h,d,s) bf16 ----------
__global__ __launch_bounds__(256)
void vtrans(const u16t* __restrict__ V, u16t* __restrict__ Vt)
{
    __shared__ u16t L[64][65];
    const int t = threadIdx.x;
    const int bh = blockIdx.y;
    const int s0 = blockIdx.x * 64;
    const u16t* src = V + ((size_t)bh * SEQ + s0) * DHEAD;
#pragma unroll
    for (int rep = 0; rep < 2; ++rep) {
        const int id = rep * 256 + t;
        const int s = id >> 3, dc = (id & 7) * 8;
        u16x8 v = *(const u16x8*)&src[(size_t)s * DHEAD + dc];
#pragma unroll
        for (int i = 0; i < 8; ++i) L[s][dc + i] = v[i];
    }
    __syncthreads();
    u16t* dstb = Vt + (size_t)bh * DHEAD * SEQ + s0;
#pragma unroll
    for (int rep = 0; rep < 2; ++rep) {
        const int id = rep * 256 + t;
        const int d = id >> 3, sc = (id & 7) * 8;
        u16x8 o;
#pragma unroll
        for (int i = 0; i < 8; ++i) o[i] = L[sc + i][d];
        *(u16x8*)&dstb[(size_t)d * SEQ + sc] = o;
    }
}

// ---------- bf16 GEMM (m97 structure + both-sides XOR swizzle) ----------
// C = A[M,1024] @ WT[N,1024]^T + bias.  LDS linear [128][64] u16; the 16B
// chunk index is XOR-swizzled with (row&7) on BOTH the global source of
// global_load_lds and the ds_read side (rule #21) -> conflict-free b128 reads.
// MODE 0: fp32 out.  MODE 1: QKV scatter -> bf16 Q(exp2-scaled)/K/V (b,h,s,d).
template <int MODE>
__global__ __launch_bounds__(256)
void gemm_bf16(const u16t* __restrict__ A, const u16t* __restrict__ BT,
               const float* __restrict__ bias, int N,
               float* __restrict__ C0, u16t* __restrict__ Qo,
               u16t* __restrict__ Ko, u16t* __restrict__ Vo)
{
    __shared__ __align__(16) u16t Al[128 * 64];
    __shared__ __align__(16) u16t Bl[128 * 64];
    const int t = threadIdx.x;
    const int lane = t & 63;
    const int g = lane >> 4, l15 = lane & 15;
    const int w = t >> 6, wr = w >> 1, wc = w & 1;
    const int m0 = blockIdx.y * 128, n0 = blockIdx.x * 128;

    // staging: wave w owns rows [w*32, w*32+32); HW writes lane -> byte lane*16,
    // i.e. row = +lane/8, chunk = lane%8.  Source chunk pre-swizzled so that
    // LDS slot (row, ch) holds tile data (row, ch ^ (row&7)).
    const int srow = w * 32;                       // wave-uniform
    const int lrow = lane >> 3;                    // 0..7
    const int lcolsw = ((lane & 7) ^ lrow) * 8;    // swizzled 16B-chunk, u16 units

    const int r7 = l15 & 7;                        // fragment row & 7 (i*16 preserves mod 8)

    f32x4 acc[4][4] = {};

    for (int k0 = 0; k0 < EMBED; k0 += 64) {
        __syncthreads();
#pragma unroll
        for (int r_ = 0; r_ < 4; ++r_) {
            const int row_ = srow + r_ * 8;
            ldsload16(&A [(size_t)(m0 + row_ + lrow) * EMBED + k0 + lcolsw], &Al[row_ * 64]);
            ldsload16(&BT[(size_t)(n0 + row_ + lrow) * EMBED + k0 + lcolsw], &Bl[row_ * 64]);
        }
        __syncthreads();
#pragma unroll
        for (int kk = 0; kk < 2; ++kk) {
            bf16x8 av[4], bv[4];
#pragma unroll
            for (int i = 0; i < 4; ++i) {
                const int chA = ((kk * 4 + g) ^ r7) * 8;   // swizzled read chunk
                av[i] = asbf(*(const u16x8*)&Al[(wr * 64 + i * 16 + l15) * 64 + chA]);
                bv[i] = asbf(*(const u16x8*)&Bl[(wc * 64 + i * 16 + l15) * 64 + chA]);
            }
#pragma unroll
            for (int i = 0; i < 4; ++i)
#pragma unroll
                for (int j = 0; j < 4; ++j)
                    acc[i][j] = mfma16(av[i], bv[j], acc[i][j]);
        }
    }

#pragma unroll
    for (int i = 0; i < 4; ++i)
#pragma unroll
        for (int j = 0; j < 4; ++j)
#pragma unroll
            for (int r = 0; r < 4; ++r) {
                const int row = m0 + wr * 64 + i * 16 + g * 4 + r;
                const int col = n0 + wc * 64 + j * 16 + l15;
                float v = acc[i][j][r] + bias[col];
                if (MODE == 0) {
                    C0[(size_t)row * N + col] = v;
                } else {
                    const int tt = col >> 10, c1 = col & 1023;
                    const int h = c1 >> 6, d = c1 & 63;
                    const int b = row >> 11, s = row & 2047;
                    if (tt == 0) v *= QS2;
                    u16t* dst = (tt == 0) ? Qo : (tt == 1 ? Ko : Vo);
                    dst[(((size_t)b * HEADS + h) * SEQ + s) * DHEAD + d] = f2bf(v);
                }
            }
}

// ---------- MFMA flash attention: QBLK=128, T14 early-issue staging ----------
// 4 waves x 32 q. K fragments and V fragments each feed 2 MFMAs (qh=0,1).
__global__ __launch_bounds__(256)
void attn_mfma(const u16t* __restrict__ Q, const u16t* __restrict__ K,
               const u16t* __restrict__ Vt, u16t* __restrict__ AO)
{
    __shared__ __align__(16) u16t Kl[64][72];   // [key][d], padded
    __shared__ __align__(16) u16t Vl[64][72];   // [d][key], padded
    const int t = threadIdx.x;
    const int lane = t & 63, wq = t >> 6;
    const int g = lane >> 4, l15 = lane & 15;
    const int bh = blockIdx.y;
    const int q0 = blockIdx.x * 128;
    const int b = bh >> 4, h = bh & 15;

    // Q fragments: 32 q-rows per wave (two 16-row groups)
    const u16t* qbase = Q + ((size_t)bh * SEQ + q0 + wq * 32) * DHEAD;
    bf16x8 qf[2][2];
#pragma unroll
    for (int qh = 0; qh < 2; ++qh)
#pragma unroll
        for (int kk = 0; kk < 2; ++kk)
            qf[qh][kk] = asbf(*(const u16x8*)&qbase[(size_t)(qh * 16 + l15) * DHEAD + kk * 32 + g * 8]);

    const int srow = t >> 3, scol = (t & 7) * 8;
    const u16t* Kb = K + (size_t)bh * SEQ * DHEAD;
    const u16t* Vb = Vt + (size_t)bh * DHEAD * SEQ;

    // prologue: stage tile 0
    {
        u16x8 k0r[2], v0r[2];
#pragma unroll
        for (int rep = 0; rep < 2; ++rep) {
            const int r = rep * 32 + srow;
            k0r[rep] = *(const u16x8*)&Kb[(size_t)r * DHEAD + scol];
            v0r[rep] = *(const u16x8*)&Vb[(size_t)r * SEQ + scol];
        }
#pragma unroll
        for (int rep = 0; rep < 2; ++rep) {
            const int r = rep * 32 + srow;
            *(u16x8*)&Kl[r][scol] = k0r[rep];
            *(u16x8*)&Vl[r][scol] = v0r[rep];
        }
    }
    __syncthreads();

    f32x4 accO[4][2] = {};
    float mrun[2] = {-1e30f, -1e30f}, lrun[2] = {0.f, 0.f};

    for (int kv0 = 0; kv0 < SEQ; kv0 += 64) {
        const bool more = (kv0 + 64 < SEQ);
        // T14: issue next tile's global loads now; write to LDS after barrier
        u16x8 kreg[2], vreg[2];
        if (more) {
#pragma unroll
            for (int rep = 0; rep < 2; ++rep) {
                const int r = rep * 32 + srow;
                kreg[rep] = *(const u16x8*)&Kb[(size_t)(kv0 + 64 + r) * DHEAD + scol];
                vreg[rep] = *(const u16x8*)&Vb[(size_t)r * SEQ + kv0 + 64 + scol];
            }
        }

        // ---- QK^T: S^T[key][q] for both q-halves ----
        f32x4 s4[4][2] = {};
#pragma unroll
        for (int kk = 0; kk < 2; ++kk)
#pragma unroll
            for (int mf = 0; mf < 4; ++mf) {
                bf16x8 a = asbf(*(const u16x8*)&Kl[mf * 16 + l15][kk * 32 + g * 8]);
                s4[mf][0] = mfma16(a, qf[0][kk], s4[mf][0]);
                s4[mf][1] = mfma16(a, qf[1][kk], s4[mf][1]);
            }

        // ---- online softmax (exp2 domain, defer-max) ----
        float mt[2];
#pragma unroll
        for (int qh = 0; qh < 2; ++qh) {
            float m = s4[0][qh][0];
#pragma unroll
            for (int mf = 0; mf < 4; ++mf)
#pragma unroll
                for (int r = 0; r < 4; ++r) m = fmaxf(m, s4[mf][qh][r]);
            m = fmaxf(m, __shfl_xor(m, 16));
            m = fmaxf(m, __shfl_xor(m, 32));
            mt[qh] = m;
        }
        const bool skip =
            __all((mt[0] - mrun[0] <= DEFER_THR) && (mt[1] - mrun[1] <= DEFER_THR)) != 0;
        float mnew[2];
#pragma unroll
        for (int qh = 0; qh < 2; ++qh)
            mnew[qh] = skip ? mrun[qh] : fmaxf(mrun[qh], mt[qh]);

        float p[4][2][4], rs[2] = {0.f, 0.f};
#pragma unroll
        for (int mf = 0; mf < 4; ++mf)
#pragma unroll
            for (int qh = 0; qh < 2; ++qh)
#pragma unroll
                for (int r = 0; r < 4; ++r) {
                    p[mf][qh][r] = __builtin_amdgcn_exp2f(s4[mf][qh][r] - mnew[qh]);
                    rs[qh] += p[mf][qh][r];
                }
#pragma unroll
        for (int qh = 0; qh < 2; ++qh) {
            rs[qh] += __shfl_xor(rs[qh], 16);
            rs[qh] += __shfl_xor(rs[qh], 32);
        }

        if (skip) {
            lrun[0] += rs[0];
            lrun[1] += rs[1];
        } else {
#pragma unroll
            for (int qh = 0; qh < 2; ++qh) {
                const float alpha = __builtin_amdgcn_exp2f(mrun[qh] - mnew[qh]);
                lrun[qh] = lrun[qh] * alpha + rs[qh];
                mrun[qh] = mnew[qh];
                float al[4];
#pragma unroll
                for (int r = 0; r < 4; ++r) al[r] = __shfl(alpha, g * 4 + r);
#pragma unroll
                for (int nf = 0; nf < 4; ++nf)
#pragma unroll
                    for (int r = 0; r < 4; ++r) accO[nf][qh][r] *= al[r];
            }
        }

        // ---- P -> bf16 (cvt_pk), k-permuted A-fragments ----
        u16x8 pu[2][2];
#pragma unroll
        for (int kk = 0; kk < 2; ++kk)
#pragma unroll
            for (int qh = 0; qh < 2; ++qh) {
                const int a = kk * 2;
                u32x4 pw;
                pw[0] = cvtpk(p[a][qh][0], p[a][qh][1]);
                pw[1] = cvtpk(p[a][qh][2], p[a][qh][3]);
                pw[2] = cvtpk(p[a + 1][qh][0], p[a + 1][qh][1]);
                pw[3] = cvtpk(p[a + 1][qh][2], p[a + 1][qh][3]);
                pu[kk][qh] = __builtin_bit_cast(u16x8, pw);
            }

        // ---- PV: V fragment shared across q-halves ----
#pragma unroll
        for (int kk = 0; kk < 2; ++kk)
#pragma unroll
            for (int nf = 0; nf < 4; ++nf) {
                const u16t* vr = &Vl[nf * 16 + l15][0];
                u16x4 lo = *(const u16x4*)&vr[kk * 32 + g * 4];
                u16x4 hi = *(const u16x4*)&vr[kk * 32 + 16 + g * 4];
                u16x8 bb = __builtin_shufflevector(lo, hi, 0, 1, 2, 3, 4, 5, 6, 7);
                accO[nf][0] = mfma16(asbf(pu[kk][0]), asbf(bb), accO[nf][0]);
                accO[nf][1] = mfma16(asbf(pu[kk][1]), asbf(bb), accO[nf][1]);
            }

        __syncthreads();                // all waves done reading Kl/Vl
        if (more) {
#pragma unroll
            for (int rep = 0; rep < 2; ++rep) {
                const int r = rep * 32 + srow;
                *(u16x8*)&Kl[r][scol] = kreg[rep];
                *(u16x8*)&Vl[r][scol] = vreg[rep];
            }
            __syncthreads();            // next tile ready
        }
    }

#pragma unroll
    for (int qh = 0; qh < 2; ++qh) {
        const float inv = 1.f / lrun[qh];
        float iv[4];
#pragma unroll
        for (int r = 0; r < 4; ++r) iv[r] = __shfl(inv, g * 4 + r);
#pragma unroll
        for (int nf = 0; nf < 4; ++nf)
#pragma unroll
            for (int r = 0; r < 4; ++r) {
                const int s = q0 + wq * 32 + qh * 16 + g * 4 + r;
                AO[((size_t)b * SEQ + s) * EMBED + h * DHEAD + nf * 16 + l15] =
                    f2bf(accO[nf][qh][r] * iv[r]);
            }
    }
}

// ---------- launch ----------
extern "C" void kernel_launch(void* const* d_in, const int* in_sizes, int n_in,
                              void* d_out, int out_size, void* d_ws, size_t ws_size,
                              hipStream_t stream)
{
    const float* x     = (const float*)d_in[0];
    const float* w_qkv = (const float*)d_in[1];
    const float* b_qkv = (const float*)d_in[2];
    const float* w_out = (const float*)d_in[3];
    const float* b_out = (const float*)d_in[4];

    u16t* xb  = (u16t*)d_ws;
    u16t* wqt = xb  + (size_t)NTOK * EMBED;
    u16t* wot = wqt + (size_t)3072 * 1024;
    u16t* Qb  = wot + (size_t)1024 * 1024;
    u16t* Kb  = Qb  + (size_t)NTOK * EMBED;
    u16t* Vb  = Kb  + (size_t)NTOK * EMBED;
    u16t* Vtb = Vb  + (size_t)NTOK * EMBED;
    u16t* AOb = Vtb + (size_t)NTOK * EMBED;

    xcvt<<<2048, 256, 0, stream>>>(x, xb);
    wtrans<<<dim3(48, 16), 256, 0, stream>>>(w_qkv, wqt, 1024, 3072);
    wtrans<<<dim3(16, 16), 256, 0, stream>>>(w_out, wot, 1024, 1024);

    gemm_bf16<1><<<dim3(24, 32), 256, 0, stream>>>(xb, wqt, b_qkv, 3072,
                                                   nullptr, Qb, Kb, Vb);
    vtrans<<<dim3(32, 32), 256, 0, stream>>>(Vb, Vtb);
    attn_mfma<<<dim3(16, 32), 256, 0, stream>>>(Qb, Kb, Vtb, AOb);
    gemm_bf16<0><<<dim3(8, 32), 256, 0, stream>>>(AOb, wot, b_out, 1024,
                                                  (float*)d_out, nullptr, nullptr, nullptr);
}

// Round 8
// 217.731 us; speedup vs baseline: 1.1150x; 1.0348x over previous
//
#include <hip/hip_runtime.h>

#define EMBED  1024
#define HEADS  16
#define DHEAD  64
#define SEQ    2048
#define BATCH  2
#define NTOK   4096
// softmax in exp2 domain: fold attention scale * log2(e) into Q pre-scale
#define QS2    (0.125f * 1.44269504089f)
#define DEFER_THR 8.0f

typedef unsigned short u16t;
typedef float f32x4 __attribute__((ext_vector_type(4)));
typedef __bf16 bf16x8 __attribute__((ext_vector_type(8)));
typedef u16t u16x8 __attribute__((ext_vector_type(8)));
typedef u16t u16x4 __attribute__((ext_vector_type(4)));
typedef unsigned u32x4 __attribute__((ext_vector_type(4)));

static __device__ __forceinline__ u16t f2bf(float f) {
    unsigned u = __builtin_bit_cast(unsigned, f);
    return (u16t)((u + 0x7fffu + ((u >> 16) & 1u)) >> 16);   // RNE
}
static __device__ __forceinline__ bf16x8 asbf(u16x8 v) {
    return __builtin_bit_cast(bf16x8, v);
}
static __device__ __forceinline__ f32x4 mfma16(bf16x8 a, bf16x8 b, f32x4 c) {
    return __builtin_amdgcn_mfma_f32_16x16x32_bf16(a, b, c, 0, 0, 0);
}
static __device__ __forceinline__ unsigned cvtpk(float lo, float hi) {
    unsigned r;
    asm("v_cvt_pk_bf16_f32 %0, %1, %2" : "=v"(r) : "v"(lo), "v"(hi));
    return r;
}

// async global->LDS, 16B per lane; LDS dest = uniform base + lane*16 (linear)
typedef const __attribute__((address_space(1))) void* as1cv;
typedef __attribute__((address_space(3))) void* as3v;
static __device__ __forceinline__ void ldsload16(const void* g, void* l) {
    __builtin_amdgcn_global_load_lds((as1cv)g, (as3v)l, 16, 0, 0);
}

// ---------- x fp32 -> bf16 ----------
__global__ __launch_bounds__(256)
void xcvt(const float* __restrict__ X, u16t* __restrict__ XB)
{
    const size_t i = ((size_t)blockIdx.x * 256 + threadIdx.x) * 8;
    float4 a = *(const float4*)&X[i];
    float4 b = *(const float4*)&X[i + 4];
    u16x8 o;
    o[0] = f2bf(a.x); o[1] = f2bf(a.y); o[2] = f2bf(a.z); o[3] = f2bf(a.w);
    o[4] = f2bf(b.x); o[5] = f2bf(b.y); o[6] = f2bf(b.z); o[7] = f2bf(b.w);
    *(u16x8*)&XB[i] = o;
}

// ---------- W [K][N] fp32 -> WT [N][K] bf16 (64x64 LDS tiles) ----------
__global__ __launch_bounds__(256)
void wtrans(const float* __restrict__ W, u16t* __restrict__ WT, int K, int N)
{
    __shared__ float L[64][65];
    const int t = threadIdx.x;
    const int k0 = blockIdx.y * 64, n0 = blockIdx.x * 64;
#pragma unroll
    for (int rep = 0; rep < 4; ++rep) {
        const int id = rep * 256 + t;
        const int kk = id >> 4, nc = (id & 15) * 4;
        float4 v = *(const float4*)&W[(size_t)(k0 + kk) * N + n0 + nc];
        L[kk][nc] = v.x; L[kk][nc + 1] = v.y; L[kk][nc + 2] = v.z; L[kk][nc + 3] = v.w;
    }
    __syncthreads();
#pragma unroll
    for (int rep = 0; rep < 2; ++rep) {
        const int id = rep * 256 + t;
        const int n = id >> 3, kc = (id & 7) * 8;
        u16x8 o;
#pragma unroll
        for (int i = 0; i < 8; ++i) o[i] = f2bf(L[kc + i][n]);
        *(u16x8*)&WT[(size_t)(n0 + n) * K + k0 + kc] = o;
    }
}

// ---------- V (b,h,s,d) bf16 -> Vt (b,h,d,s) bf16 ----------
__global__ __launch_bounds__(256)
void vtrans(const u16t* __restrict__ V, u16t* __restrict__ Vt)
{
    __shared__ u16t L[64][65];
    const int t = threadIdx.x;
    const int bh = blockIdx.y;
    const int s0 = blockIdx.x * 64;
    const u16t* src = V + ((size_t)bh * SEQ + s0) * DHEAD;
#pragma unroll
    for (int rep = 0; rep < 2; ++rep) {
        const int id = rep * 256 + t;
        const int s = id >> 3, dc = (id & 7) * 8;
        u16x8 v = *(const u16x8*)&src[(size_t)s * DHEAD + dc];
#pragma unroll
        for (int i = 0; i < 8; ++i) L[s][dc + i] = v[i];
    }
    __syncthreads();
    u16t* dstb = Vt + (size_t)bh * DHEAD * SEQ + s0;
#pragma unroll
    for (int rep = 0; rep < 2; ++rep) {
        const int id = rep * 256 + t;
        const int d = id >> 3, sc = (id & 7) * 8;
        u16x8 o;
#pragma unroll
        for (int i = 0; i < 8; ++i) o[i] = L[sc + i][d];
        *(u16x8*)&dstb[(size_t)d * SEQ + sc] = o;
    }
}

// ---------- bf16 GEMM: 2-phase dbuf + both-sides XOR swizzle ----------
// C[M,N-tile] = A[M,1024] @ WT[N,1024]^T + bias.  BM = FM*32 (FM=4: 128x128
// QKV; FM=2: 64x128 proj, grid 2x denser for 2 blocks/CU).  T3-minimum:
// stage(t+1) issued BEFORE compute(t); one barrier per K-step (implicit
// vmcnt0+lgkm drain).  LDS linear; 16B-chunk XOR-swizzled on BOTH the
// global source and the ds_read side (rule #21) -> conflict-free b128.
// MODE 0: fp32 out.  MODE 1: QKV scatter -> bf16 Q(exp2-scaled)/K/V.
template <int MODE, int FM>
__global__ __launch_bounds__(256)
void gemm_bf16(const u16t* __restrict__ A, const u16t* __restrict__ BT,
               const float* __restrict__ bias, int N,
               float* __restrict__ C0, u16t* __restrict__ Qo,
               u16t* __restrict__ Ko, u16t* __restrict__ Vo)
{
    constexpr int BM = FM * 32;
    __shared__ __align__(16) u16t Al[2][BM * 64];
    __shared__ __align__(16) u16t Bl[2][128 * 64];
    const int t = threadIdx.x;
    const int lane = t & 63;
    const int g = lane >> 4, l15 = lane & 15;
    const int w = t >> 6, wr = w >> 1, wc = w & 1;
    const int m0 = blockIdx.y * BM, n0 = blockIdx.x * 128;

    // staging: HW writes lane -> byte lane*16 (row = lane/8, chunk = lane%8).
    // Source chunk pre-swizzled: LDS slot (row, ch) holds data (row, ch^(row&7)).
    const int asrow = w * (FM * 8);                // wave's A rows
    const int bsrow = w * 32;                      // wave's B rows
    const int lrow = lane >> 3;                    // 0..7
    const int lcolsw = ((lane & 7) ^ lrow) * 8;    // swizzled 16B-chunk, u16 units

    const int r7 = l15 & 7;                        // fragment row & 7

#define GSTAGE(buf, k0)                                                           \
    {                                                                             \
        _Pragma("unroll")                                                         \
        for (int r_ = 0; r_ < FM; ++r_) {                                         \
            const int row_ = asrow + r_ * 8;                                      \
            ldsload16(&A[(size_t)(m0 + row_ + lrow) * EMBED + (k0) + lcolsw],     \
                      &Al[buf][row_ * 64]);                                       \
        }                                                                         \
        _Pragma("unroll")                                                         \
        for (int r_ = 0; r_ < 4; ++r_) {                                          \
            const int row_ = bsrow + r_ * 8;                                      \
            ldsload16(&BT[(size_t)(n0 + row_ + lrow) * EMBED + (k0) + lcolsw],    \
                      &Bl[buf][row_ * 64]);                                       \
        }                                                                         \
    }

    f32x4 acc[FM][4] = {};

    GSTAGE(0, 0);
    __syncthreads();                    // tile 0 resident

    int cur = 0;
    for (int k0 = 0; k0 < EMBED; k0 += 64) {
        if (k0 + 64 < EMBED) GSTAGE(cur ^ 1, k0 + 64);   // prefetch next tile
        const u16t* Ab = &Al[cur][0];
        const u16t* Bb = &Bl[cur][0];
#pragma unroll
        for (int kk = 0; kk < 2; ++kk) {
            const int chA = ((kk * 4 + g) ^ r7) * 8;     // swizzled read chunk
            bf16x8 av[FM], bv[4];
#pragma unroll
            for (int i = 0; i < FM; ++i)
                av[i] = asbf(*(const u16x8*)&Ab[(wr * (FM * 16) + i * 16 + l15) * 64 + chA]);
#pragma unroll
            for (int j = 0; j < 4; ++j)
                bv[j] = asbf(*(const u16x8*)&Bb[(wc * 64 + j * 16 + l15) * 64 + chA]);
#pragma unroll
            for (int i = 0; i < FM; ++i)
#pragma unroll
                for (int j = 0; j < 4; ++j)
                    acc[i][j] = mfma16(av[i], bv[j], acc[i][j]);
        }
        __syncthreads();                // drains vmcnt(0): next tile ready
        cur ^= 1;
    }
#undef GSTAGE

#pragma unroll
    for (int i = 0; i < FM; ++i)
#pragma unroll
        for (int j = 0; j < 4; ++j)
#pragma unroll
            for (int r = 0; r < 4; ++r) {
                const int row = m0 + wr * (FM * 16) + i * 16 + g * 4 + r;
                const int col = n0 + wc * 64 + j * 16 + l15;
                float v = acc[i][j][r] + bias[col];
                if (MODE == 0) {
                    C0[(size_t)row * N + col] = v;
                } else {
                    const int tt = col >> 10, c1 = col & 1023;
                    const int h = c1 >> 6, d = c1 & 63;
                    const int b = row >> 11, s = row & 2047;
                    if (tt == 0) v *= QS2;
                    u16t* dst = (tt == 0) ? Qo : (tt == 1 ? Ko : Vo);
                    dst[(((size_t)b * HEADS + h) * SEQ + s) * DHEAD + d] = f2bf(v);
                }
            }
}

// ---------- MFMA flash attention: QBLK=128, T14 staging, T5 setprio ----------
__global__ __launch_bounds__(256)
void attn_mfma(const u16t* __restrict__ Q, const u16t* __restrict__ K,
               const u16t* __restrict__ Vt, u16t* __restrict__ AO)
{
    __shared__ __align__(16) u16t Kl[64][72];   // [key][d], padded
    __shared__ __align__(16) u16t Vl[64][72];   // [d][key], padded
    const int t = threadIdx.x;
    const int lane = t & 63, wq = t >> 6;
    const int g = lane >> 4, l15 = lane & 15;
    const int bh = blockIdx.y;
    const int q0 = blockIdx.x * 128;
    const int b = bh >> 4, h = bh & 15;

    const u16t* qbase = Q + ((size_t)bh * SEQ + q0 + wq * 32) * DHEAD;
    bf16x8 qf[2][2];
#pragma unroll
    for (int qh = 0; qh < 2; ++qh)
#pragma unroll
        for (int kk = 0; kk < 2; ++kk)
            qf[qh][kk] = asbf(*(const u16x8*)&qbase[(size_t)(qh * 16 + l15) * DHEAD + kk * 32 + g * 8]);

    const int srow = t >> 3, scol = (t & 7) * 8;
    const u16t* Kb = K + (size_t)bh * SEQ * DHEAD;
    const u16t* Vb = Vt + (size_t)bh * DHEAD * SEQ;

    // prologue: stage tile 0
    {
        u16x8 k0r[2], v0r[2];
#pragma unroll
        for (int rep = 0; rep < 2; ++rep) {
            const int r = rep * 32 + srow;
            k0r[rep] = *(const u16x8*)&Kb[(size_t)r * DHEAD + scol];
            v0r[rep] = *(const u16x8*)&Vb[(size_t)r * SEQ + scol];
        }
#pragma unroll
        for (int rep = 0; rep < 2; ++rep) {
            const int r = rep * 32 + srow;
            *(u16x8*)&Kl[r][scol] = k0r[rep];
            *(u16x8*)&Vl[r][scol] = v0r[rep];
        }
    }
    __syncthreads();

    f32x4 accO[4][2] = {};
    float mrun[2] = {-1e30f, -1e30f}, lrun[2] = {0.f, 0.f};

    for (int kv0 = 0; kv0 < SEQ; kv0 += 64) {
        const bool more = (kv0 + 64 < SEQ);
        // T14: issue next tile's global loads now; write to LDS after barrier
        u16x8 kreg[2], vreg[2];
        if (more) {
#pragma unroll
            for (int rep = 0; rep < 2; ++rep) {
                const int r = rep * 32 + srow;
                kreg[rep] = *(const u16x8*)&Kb[(size_t)(kv0 + 64 + r) * DHEAD + scol];
                vreg[rep] = *(const u16x8*)&Vb[(size_t)r * SEQ + kv0 + 64 + scol];
            }
        }

        // ---- QK^T: S^T[key][q] for both q-halves ----
        f32x4 s4[4][2] = {};
        __builtin_amdgcn_s_setprio(1);
#pragma unroll
        for (int kk = 0; kk < 2; ++kk)
#pragma unroll
            for (int mf = 0; mf < 4; ++mf) {
                bf16x8 a = asbf(*(const u16x8*)&Kl[mf * 16 + l15][kk * 32 + g * 8]);
                s4[mf][0] = mfma16(a, qf[0][kk], s4[mf][0]);
                s4[mf][1] = mfma16(a, qf[1][kk], s4[mf][1]);
            }
        __builtin_amdgcn_s_setprio(0);

        // ---- online softmax (exp2 domain, defer-max) ----
        float mt[2];
#pragma unroll
        for (int qh = 0; qh < 2; ++qh) {
            float m = s4[0][qh][0];
#pragma unroll
            for (int mf = 0; mf < 4; ++mf)
#pragma unroll
                for (int r = 0; r < 4; ++r) m = fmaxf(m, s4[mf][qh][r]);
            m = fmaxf(m, __shfl_xor(m, 16));
            m = fmaxf(m, __shfl_xor(m, 32));
            mt[qh] = m;
        }
        const bool skip =
            __all((mt[0] - mrun[0] <= DEFER_THR) && (mt[1] - mrun[1] <= DEFER_THR)) != 0;
        float mnew[2];
#pragma unroll
        for (int qh = 0; qh < 2; ++qh)
            mnew[qh] = skip ? mrun[qh] : fmaxf(mrun[qh], mt[qh]);

        float p[4][2][4], rs[2] = {0.f, 0.f};
#pragma unroll
        for (int mf = 0; mf < 4; ++mf)
#pragma unroll
            for (int qh = 0; qh < 2; ++qh)
#pragma unroll
                for (int r = 0; r < 4; ++r) {
                    p[mf][qh][r] = __builtin_amdgcn_exp2f(s4[mf][qh][r] - mnew[qh]);
                    rs[qh] += p[mf][qh][r];
                }
#pragma unroll
        for (int qh = 0; qh < 2; ++qh) {
            rs[qh] += __shfl_xor(rs[qh], 16);
            rs[qh] += __shfl_xor(rs[qh], 32);
        }

        if (skip) {
            lrun[0] += rs[0];
            lrun[1] += rs[1];
        } else {
#pragma unroll
            for (int qh = 0; qh < 2; ++qh) {
                const float alpha = __builtin_amdgcn_exp2f(mrun[qh] - mnew[qh]);
                lrun[qh] = lrun[qh] * alpha + rs[qh];
                mrun[qh] = mnew[qh];
                float al[4];
#pragma unroll
                for (int r = 0; r < 4; ++r) al[r] = __shfl(alpha, g * 4 + r);
#pragma unroll
                for (int nf = 0; nf < 4; ++nf)
#pragma unroll
                    for (int r = 0; r < 4; ++r) accO[nf][qh][r] *= al[r];
            }
        }

        // ---- P -> bf16 (cvt_pk), k-permuted A-fragments ----
        u16x8 pu[2][2];
#pragma unroll
        for (int kk = 0; kk < 2; ++kk)
#pragma unroll
            for (int qh = 0; qh < 2; ++qh) {
                const int a = kk * 2;
                u32x4 pw;
                pw[0] = cvtpk(p[a][qh][0], p[a][qh][1]);
                pw[1] = cvtpk(p[a][qh][2], p[a][qh][3]);
                pw[2] = cvtpk(p[a + 1][qh][0], p[a + 1][qh][1]);
                pw[3] = cvtpk(p[a + 1][qh][2], p[a + 1][qh][3]);
                pu[kk][qh] = __builtin_bit_cast(u16x8, pw);
            }

        // ---- PV: V fragment shared across q-halves ----
        __builtin_amdgcn_s_setprio(1);
#pragma unroll
        for (int kk = 0; kk < 2; ++kk)
#pragma unroll
            for (int nf = 0; nf < 4; ++nf) {
                const u16t* vr = &Vl[nf * 16 + l15][0];
                u16x4 lo = *(const u16x4*)&vr[kk * 32 + g * 4];
                u16x4 hi = *(const u16x4*)&vr[kk * 32 + 16 + g * 4];
                u16x8 bb = __builtin_shufflevector(lo, hi, 0, 1, 2, 3, 4, 5, 6, 7);
                accO[nf][0] = mfma16(asbf(pu[kk][0]), asbf(bb), accO[nf][0]);
                accO[nf][1] = mfma16(asbf(pu[kk][1]), asbf(bb), accO[nf][1]);
            }
        __builtin_amdgcn_s_setprio(0);

        __syncthreads();                // all waves done reading Kl/Vl
        if (more) {
#pragma unroll
            for (int rep = 0; rep < 2; ++rep) {
                const int r = rep * 32 + srow;
                *(u16x8*)&Kl[r][scol] = kreg[rep];
                *(u16x8*)&Vl[r][scol] = vreg[rep];
            }
            __syncthreads();            // next tile ready
        }
    }

#pragma unroll
    for (int qh = 0; qh < 2; ++qh) {
        const float inv = 1.f / lrun[qh];
        float iv[4];
#pragma unroll
        for (int r = 0; r < 4; ++r) iv[r] = __shfl(inv, g * 4 + r);
#pragma unroll
        for (int nf = 0; nf < 4; ++nf)
#pragma unroll
            for (int r = 0; r < 4; ++r) {
                const int s = q0 + wq * 32 + qh * 16 + g * 4 + r;
                AO[((size_t)b * SEQ + s) * EMBED + h * DHEAD + nf * 16 + l15] =
                    f2bf(accO[nf][qh][r] * iv[r]);
            }
    }
}

// ---------- launch ----------
extern "C" void kernel_launch(void* const* d_in, const int* in_sizes, int n_in,
                              void* d_out, int out_size, void* d_ws, size_t ws_size,
                              hipStream_t stream)
{
    const float* x     = (const float*)d_in[0];
    const float* w_qkv = (const float*)d_in[1];
    const float* b_qkv = (const float*)d_in[2];
    const float* w_out = (const float*)d_in[3];
    const float* b_out = (const float*)d_in[4];

    u16t* xb  = (u16t*)d_ws;
    u16t* wqt = xb  + (size_t)NTOK * EMBED;
    u16t* wot = wqt + (size_t)3072 * 1024;
    u16t* Qb  = wot + (size_t)1024 * 1024;
    u16t* Kb  = Qb  + (size_t)NTOK * EMBED;
    u16t* Vb  = Kb  + (size_t)NTOK * EMBED;
    u16t* Vtb = Vb  + (size_t)NTOK * EMBED;
    u16t* AOb = Vtb + (size_t)NTOK * EMBED;

    xcvt<<<2048, 256, 0, stream>>>(x, xb);
    wtrans<<<dim3(48, 16), 256, 0, stream>>>(w_qkv, wqt, 1024, 3072);
    wtrans<<<dim3(16, 16), 256, 0, stream>>>(w_out, wot, 1024, 1024);

    // QKV: 128x128 tiles, grid 24x32 = 768 blocks
    gemm_bf16<1, 4><<<dim3(24, 32), 256, 0, stream>>>(xb, wqt, b_qkv, 3072,
                                                      nullptr, Qb, Kb, Vb);
    vtrans<<<dim3(32, 32), 256, 0, stream>>>(Vb, Vtb);
    attn_mfma<<<dim3(16, 32), 256, 0, stream>>>(Qb, Kb, Vtb, AOb);
    // proj: 64x128 tiles, grid 8x64 = 512 blocks (2 blocks/CU)
    gemm_bf16<0, 2><<<dim3(8, 64), 256, 0, stream>>>(AOb, wot, b_out, 1024,
                                                     (float*)d_out, nullptr, nullptr, nullptr);
}

// Round 9
// 212.310 us; speedup vs baseline: 1.1434x; 1.0255x over previous
//
#include <hip/hip_runtime.h>

#define EMBED  1024
#define HEADS  16
#define DHEAD  64
#define SEQ    2048
#define BATCH  2
#define NTOK   4096
// softmax in exp2 domain: fold attention scale * log2(e) into Q pre-scale
#define QS2    (0.125f * 1.44269504089f)
#define DEFER_THR 8.0f

typedef unsigned short u16t;
typedef float f32x4 __attribute__((ext_vector_type(4)));
typedef __bf16 bf16x8 __attribute__((ext_vector_type(8)));
typedef u16t u16x8 __attribute__((ext_vector_type(8)));
typedef u16t u16x4 __attribute__((ext_vector_type(4)));
typedef unsigned u32x4 __attribute__((ext_vector_type(4)));

static __device__ __forceinline__ u16t f2bf(float f) {
    unsigned u = __builtin_bit_cast(unsigned, f);
    return (u16t)((u + 0x7fffu + ((u >> 16) & 1u)) >> 16);   // RNE
}
static __device__ __forceinline__ bf16x8 asbf(u16x8 v) {
    return __builtin_bit_cast(bf16x8, v);
}
static __device__ __forceinline__ f32x4 mfma16(bf16x8 a, bf16x8 b, f32x4 c) {
    return __builtin_amdgcn_mfma_f32_16x16x32_bf16(a, b, c, 0, 0, 0);
}
static __device__ __forceinline__ unsigned cvtpk(float lo, float hi) {
    unsigned r;
    asm("v_cvt_pk_bf16_f32 %0, %1, %2" : "=v"(r) : "v"(lo), "v"(hi));
    return r;
}

// async global->LDS, 16B per lane; LDS dest = uniform base + lane*16 (linear)
typedef const __attribute__((address_space(1))) void* as1cv;
typedef __attribute__((address_space(3))) void* as3v;
static __device__ __forceinline__ void ldsload16(const void* g, void* l) {
    __builtin_amdgcn_global_load_lds((as1cv)g, (as3v)l, 16, 0, 0);
}

// ---------- x fp32 -> bf16 ----------
__global__ __launch_bounds__(256)
void xcvt(const float* __restrict__ X, u16t* __restrict__ XB)
{
    const size_t i = ((size_t)blockIdx.x * 256 + threadIdx.x) * 8;
    float4 a = *(const float4*)&X[i];
    float4 b = *(const float4*)&X[i + 4];
    u16x8 o;
    o[0] = f2bf(a.x); o[1] = f2bf(a.y); o[2] = f2bf(a.z); o[3] = f2bf(a.w);
    o[4] = f2bf(b.x); o[5] = f2bf(b.y); o[6] = f2bf(b.z); o[7] = f2bf(b.w);
    *(u16x8*)&XB[i] = o;
}

// ---------- W [K][N] fp32 -> WT [N][K] bf16 (64x64 LDS tiles) ----------
__global__ __launch_bounds__(256)
void wtrans(const float* __restrict__ W, u16t* __restrict__ WT, int K, int N)
{
    __shared__ float L[64][65];
    const int t = threadIdx.x;
    const int k0 = blockIdx.y * 64, n0 = blockIdx.x * 64;
#pragma unroll
    for (int rep = 0; rep < 4; ++rep) {
        const int id = rep * 256 + t;
        const int kk = id >> 4, nc = (id & 15) * 4;
        float4 v = *(const float4*)&W[(size_t)(k0 + kk) * N + n0 + nc];
        L[kk][nc] = v.x; L[kk][nc + 1] = v.y; L[kk][nc + 2] = v.z; L[kk][nc + 3] = v.w;
    }
    __syncthreads();
#pragma unroll
    for (int rep = 0; rep < 2; ++rep) {
        const int id = rep * 256 + t;
        const int n = id >> 3, kc = (id & 7) * 8;
        u16x8 o;
#pragma unroll
        for (int i = 0; i < 8; ++i) o[i] = f2bf(L[kc + i][n]);
        *(u16x8*)&WT[(size_t)(n0 + n) * K + k0 + kc] = o;
    }
}

// ---------- V (b,h,s,d) bf16 -> Vt (b,h,d,s) bf16 ----------
__global__ __launch_bounds__(256)
void vtrans(const u16t* __restrict__ V, u16t* __restrict__ Vt)
{
    __shared__ u16t L[64][65];
    const int t = threadIdx.x;
    const int bh = blockIdx.y;
    const int s0 = blockIdx.x * 64;
    const u16t* src = V + ((size_t)bh * SEQ + s0) * DHEAD;
#pragma unroll
    for (int rep = 0; rep < 2; ++rep) {
        const int id = rep * 256 + t;
        const int s = id >> 3, dc = (id & 7) * 8;
        u16x8 v = *(const u16x8*)&src[(size_t)s * DHEAD + dc];
#pragma unroll
        for (int i = 0; i < 8; ++i) L[s][dc + i] = v[i];
    }
    __syncthreads();
    u16t* dstb = Vt + (size_t)bh * DHEAD * SEQ + s0;
#pragma unroll
    for (int rep = 0; rep < 2; ++rep) {
        const int id = rep * 256 + t;
        const int d = id >> 3, sc = (id & 7) * 8;
        u16x8 o;
#pragma unroll
        for (int i = 0; i < 8; ++i) o[i] = L[sc + i][d];
        *(u16x8*)&dstb[(size_t)d * SEQ + sc] = o;
    }
}

// ---------- bf16 GEMM: dbuf + counted vmcnt (T4) + XCD swizzle (T1) ----------
// C[M,N-tile] = A[M,1024] @ WT[N,1024]^T + bias.  BM = FM*32.
// Schedule/iter t: STAGE(t+1)->buf^1 ; s_waitcnt vmcnt(8|6) [= tile-t loads
// retired, oldest-first per m135] ; s_barrier ; compute(buf) ; s_barrier
// [frees buf^1's reader set before next overwrite].  Last iter: vmcnt(0).
// LDS linear; 16B chunks XOR-swizzled on BOTH global source and ds_read.
// MODE 0: fp32 out (N=1024, grid 8x64).  MODE 1: QKV scatter (N=3072, 24x32).
template <int MODE, int FM>
__global__ __launch_bounds__(256)
void gemm_bf16(const u16t* __restrict__ A, const u16t* __restrict__ BT,
               const float* __restrict__ bias, int N,
               float* __restrict__ C0, u16t* __restrict__ Qo,
               u16t* __restrict__ Ko, u16t* __restrict__ Vo)
{
    constexpr int BM = FM * 32;
    constexpr int GX = (MODE == 1) ? 24 : 8;       // grid x (N/128), compile-time
    __shared__ __align__(16) u16t Al[2][BM * 64];
    __shared__ __align__(16) u16t Bl[2][128 * 64];
    const int t = threadIdx.x;
    const int lane = t & 63;
    const int g = lane >> 4, l15 = lane & 15;
    const int w = t >> 6, wr = w >> 1, wc = w & 1;

    // T1: XCD-aware chunked remap (bijective: nwg % 8 == 0 for both grids)
    const int nwg = GX * gridDim.y;
    const int wgid = blockIdx.y * GX + blockIdx.x;
    const int cpx = nwg >> 3;
    const int sw = (wgid & 7) * cpx + (wgid >> 3);
    const int m0 = (sw / GX) * BM, n0 = (sw % GX) * 128;

    // staging: HW writes lane -> byte lane*16 (row = lane/8, chunk = lane%8).
    // Source chunk pre-swizzled: LDS slot (row, ch) holds data (row, ch^(row&7)).
    const int asrow = w * (FM * 8);                // wave's A rows
    const int bsrow = w * 32;                      // wave's B rows
    const int lrow = lane >> 3;                    // 0..7
    const int lcolsw = ((lane & 7) ^ lrow) * 8;    // swizzled 16B-chunk, u16 units

    const int r7 = l15 & 7;                        // fragment row & 7

#define GSTAGE(buf, k0)                                                           \
    {                                                                             \
        _Pragma("unroll")                                                         \
        for (int r_ = 0; r_ < FM; ++r_) {                                         \
            const int row_ = asrow + r_ * 8;                                      \
            ldsload16(&A[(size_t)(m0 + row_ + lrow) * EMBED + (k0) + lcolsw],     \
                      &Al[buf][row_ * 64]);                                       \
        }                                                                         \
        _Pragma("unroll")                                                         \
        for (int r_ = 0; r_ < 4; ++r_) {                                          \
            const int row_ = bsrow + r_ * 8;                                      \
            ldsload16(&BT[(size_t)(n0 + row_ + lrow) * EMBED + (k0) + lcolsw],    \
                      &Bl[buf][row_ * 64]);                                       \
        }                                                                         \
    }

    f32x4 acc[FM][4] = {};

    GSTAGE(0, 0);
    asm volatile("s_waitcnt vmcnt(0)" ::: "memory");
    __builtin_amdgcn_s_barrier();

    int cur = 0;
    for (int k0 = 0; k0 < EMBED; k0 += 64) {
        const bool more = (k0 + 64 < EMBED);
        if (more) {
            GSTAGE(cur ^ 1, k0 + 64);              // prefetch next tile
            // wait only for tile-t loads (the FM+4 just-issued stay in flight)
            if constexpr (FM == 4) asm volatile("s_waitcnt vmcnt(8)" ::: "memory");
            else                   asm volatile("s_waitcnt vmcnt(6)" ::: "memory");
        } else {
            asm volatile("s_waitcnt vmcnt(0)" ::: "memory");
        }
        __builtin_amdgcn_s_barrier();              // tile t visible to all waves
        __builtin_amdgcn_sched_barrier(0);

        const u16t* Ab = &Al[cur][0];
        const u16t* Bb = &Bl[cur][0];
#pragma unroll
        for (int kk = 0; kk < 2; ++kk) {
            const int chA = ((kk * 4 + g) ^ r7) * 8;     // swizzled read chunk
            bf16x8 av[FM], bv[4];
#pragma unroll
            for (int i = 0; i < FM; ++i)
                av[i] = asbf(*(const u16x8*)&Ab[(wr * (FM * 16) + i * 16 + l15) * 64 + chA]);
#pragma unroll
            for (int j = 0; j < 4; ++j)
                bv[j] = asbf(*(const u16x8*)&Bb[(wc * 64 + j * 16 + l15) * 64 + chA]);
#pragma unroll
            for (int i = 0; i < FM; ++i)
#pragma unroll
                for (int j = 0; j < 4; ++j)
                    acc[i][j] = mfma16(av[i], bv[j], acc[i][j]);
        }
        __builtin_amdgcn_s_barrier();              // all waves done reading buf
        cur ^= 1;
    }
#undef GSTAGE

#pragma unroll
    for (int i = 0; i < FM; ++i)
#pragma unroll
        for (int j = 0; j < 4; ++j)
#pragma unroll
            for (int r = 0; r < 4; ++r) {
                const int row = m0 + wr * (FM * 16) + i * 16 + g * 4 + r;
                const int col = n0 + wc * 64 + j * 16 + l15;
                float v = acc[i][j][r] + bias[col];
                if (MODE == 0) {
                    C0[(size_t)row * N + col] = v;
                } else {
                    const int tt = col >> 10, c1 = col & 1023;
                    const int h = c1 >> 6, d = c1 & 63;
                    const int b = row >> 11, s = row & 2047;
                    if (tt == 0) v *= QS2;
                    u16t* dst = (tt == 0) ? Qo : (tt == 1 ? Ko : Vo);
                    dst[(((size_t)b * HEADS + h) * SEQ + s) * DHEAD + d] = f2bf(v);
                }
            }
}

// ---------- MFMA flash attention: QBLK=128, T14 staging, T5 setprio ----------
// (unchanged this round -- control)
__global__ __launch_bounds__(256)
void attn_mfma(const u16t* __restrict__ Q, const u16t* __restrict__ K,
               const u16t* __restrict__ Vt, u16t* __restrict__ AO)
{
    __shared__ __align__(16) u16t Kl[64][72];   // [key][d], padded
    __shared__ __align__(16) u16t Vl[64][72];   // [d][key], padded
    const int t = threadIdx.x;
    const int lane = t & 63, wq = t >> 6;
    const int g = lane >> 4, l15 = lane & 15;
    const int bh = blockIdx.y;
    const int q0 = blockIdx.x * 128;
    const int b = bh >> 4, h = bh & 15;

    const u16t* qbase = Q + ((size_t)bh * SEQ + q0 + wq * 32) * DHEAD;
    bf16x8 qf[2][2];
#pragma unroll
    for (int qh = 0; qh < 2; ++qh)
#pragma unroll
        for (int kk = 0; kk < 2; ++kk)
            qf[qh][kk] = asbf(*(const u16x8*)&qbase[(size_t)(qh * 16 + l15) * DHEAD + kk * 32 + g * 8]);

    const int srow = t >> 3, scol = (t & 7) * 8;
    const u16t* Kb = K + (size_t)bh * SEQ * DHEAD;
    const u16t* Vb = Vt + (size_t)bh * DHEAD * SEQ;

    // prologue: stage tile 0
    {
        u16x8 k0r[2], v0r[2];
#pragma unroll
        for (int rep = 0; rep < 2; ++rep) {
            const int r = rep * 32 + srow;
            k0r[rep] = *(const u16x8*)&Kb[(size_t)r * DHEAD + scol];
            v0r[rep] = *(const u16x8*)&Vb[(size_t)r * SEQ + scol];
        }
#pragma unroll
        for (int rep = 0; rep < 2; ++rep) {
            const int r = rep * 32 + srow;
            *(u16x8*)&Kl[r][scol] = k0r[rep];
            *(u16x8*)&Vl[r][scol] = v0r[rep];
        }
    }
    __syncthreads();

    f32x4 accO[4][2] = {};
    float mrun[2] = {-1e30f, -1e30f}, lrun[2] = {0.f, 0.f};

    for (int kv0 = 0; kv0 < SEQ; kv0 += 64) {
        const bool more = (kv0 + 64 < SEQ);
        u16x8 kreg[2], vreg[2];
        if (more) {
#pragma unroll
            for (int rep = 0; rep < 2; ++rep) {
                const int r = rep * 32 + srow;
                kreg[rep] = *(const u16x8*)&Kb[(size_t)(kv0 + 64 + r) * DHEAD + scol];
                vreg[rep] = *(const u16x8*)&Vb[(size_t)r * SEQ + kv0 + 64 + scol];
            }
        }

        // ---- QK^T: S^T[key][q] for both q-halves ----
        f32x4 s4[4][2] = {};
        __builtin_amdgcn_s_setprio(1);
#pragma unroll
        for (int kk = 0; kk < 2; ++kk)
#pragma unroll
            for (int mf = 0; mf < 4; ++mf) {
                bf16x8 a = asbf(*(const u16x8*)&Kl[mf * 16 + l15][kk * 32 + g * 8]);
                s4[mf][0] = mfma16(a, qf[0][kk], s4[mf][0]);
                s4[mf][1] = mfma16(a, qf[1][kk], s4[mf][1]);
            }
        __builtin_amdgcn_s_setprio(0);

        // ---- online softmax (exp2 domain, defer-max) ----
        float mt[2];
#pragma unroll
        for (int qh = 0; qh < 2; ++qh) {
            float m = s4[0][qh][0];
#pragma unroll
            for (int mf = 0; mf < 4; ++mf)
#pragma unroll
                for (int r = 0; r < 4; ++r) m = fmaxf(m, s4[mf][qh][r]);
            m = fmaxf(m, __shfl_xor(m, 16));
            m = fmaxf(m, __shfl_xor(m, 32));
            mt[qh] = m;
        }
        const bool skip =
            __all((mt[0] - mrun[0] <= DEFER_THR) && (mt[1] - mrun[1] <= DEFER_THR)) != 0;
        float mnew[2];
#pragma unroll
        for (int qh = 0; qh < 2; ++qh)
            mnew[qh] = skip ? mrun[qh] : fmaxf(mrun[qh], mt[qh]);

        float p[4][2][4], rs[2] = {0.f, 0.f};
#pragma unroll
        for (int mf = 0; mf < 4; ++mf)
#pragma unroll
            for (int qh = 0; qh < 2; ++qh)
#pragma unroll
                for (int r = 0; r < 4; ++r) {
                    p[mf][qh][r] = __builtin_amdgcn_exp2f(s4[mf][qh][r] - mnew[qh]);
                    rs[qh] += p[mf][qh][r];
                }
#pragma unroll
        for (int qh = 0; qh < 2; ++qh) {
            rs[qh] += __shfl_xor(rs[qh], 16);
            rs[qh] += __shfl_xor(rs[qh], 32);
        }

        if (skip) {
            lrun[0] += rs[0];
            lrun[1] += rs[1];
        } else {
#pragma unroll
            for (int qh = 0; qh < 2; ++qh) {
                const float alpha = __builtin_amdgcn_exp2f(mrun[qh] - mnew[qh]);
                lrun[qh] = lrun[qh] * alpha + rs[qh];
                mrun[qh] = mnew[qh];
                float al[4];
#pragma unroll
                for (int r = 0; r < 4; ++r) al[r] = __shfl(alpha, g * 4 + r);
#pragma unroll
                for (int nf = 0; nf < 4; ++nf)
#pragma unroll
                    for (int r = 0; r < 4; ++r) accO[nf][qh][r] *= al[r];
            }
        }

        // ---- P -> bf16 (cvt_pk), k-permuted A-fragments ----
        u16x8 pu[2][2];
#pragma unroll
        for (int kk = 0; kk < 2; ++kk)
#pragma unroll
            for (int qh = 0; qh < 2; ++qh) {
                const int a = kk * 2;
                u32x4 pw;
                pw[0] = cvtpk(p[a][qh][0], p[a][qh][1]);
                pw[1] = cvtpk(p[a][qh][2], p[a][qh][3]);
                pw[2] = cvtpk(p[a + 1][qh][0], p[a + 1][qh][1]);
                pw[3] = cvtpk(p[a + 1][qh][2], p[a + 1][qh][3]);
                pu[kk][qh] = __builtin_bit_cast(u16x8, pw);
            }

        // ---- PV: V fragment shared across q-halves ----
        __builtin_amdgcn_s_setprio(1);
#pragma unroll
        for (int kk = 0; kk < 2; ++kk)
#pragma unroll
            for (int nf = 0; nf < 4; ++nf) {
                const u16t* vr = &Vl[nf * 16 + l15][0];
                u16x4 lo = *(const u16x4*)&vr[kk * 32 + g * 4];
                u16x4 hi = *(const u16x4*)&vr[kk * 32 + 16 + g * 4];
                u16x8 bb = __builtin_shufflevector(lo, hi, 0, 1, 2, 3, 4, 5, 6, 7);
                accO[nf][0] = mfma16(asbf(pu[kk][0]), asbf(bb), accO[nf][0]);
                accO[nf][1] = mfma16(asbf(pu[kk][1]), asbf(bb), accO[nf][1]);
            }
        __builtin_amdgcn_s_setprio(0);

        __syncthreads();                // all waves done reading Kl/Vl
        if (more) {
#pragma unroll
            for (int rep = 0; rep < 2; ++rep) {
                const int r = rep * 32 + srow;
                *(u16x8*)&Kl[r][scol] = kreg[rep];
                *(u16x8*)&Vl[r][scol] = vreg[rep];
            }
            __syncthreads();            // next tile ready
        }
    }

#pragma unroll
    for (int qh = 0; qh < 2; ++qh) {
        const float inv = 1.f / lrun[qh];
        float iv[4];
#pragma unroll
        for (int r = 0; r < 4; ++r) iv[r] = __shfl(inv, g * 4 + r);
#pragma unroll
        for (int nf = 0; nf < 4; ++nf)
#pragma unroll
            for (int r = 0; r < 4; ++r) {
                const int s = q0 + wq * 32 + qh * 16 + g * 4 + r;
                AO[((size_t)b * SEQ + s) * EMBED + h * DHEAD + nf * 16 + l15] =
                    f2bf(accO[nf][qh][r] * iv[r]);
            }
    }
}

// ---------- launch ----------
extern "C" void kernel_launch(void* const* d_in, const int* in_sizes, int n_in,
                              void* d_out, int out_size, void* d_ws, size_t ws_size,
                              hipStream_t stream)
{
    const float* x     = (const float*)d_in[0];
    const float* w_qkv = (const float*)d_in[1];
    const float* b_qkv = (const float*)d_in[2];
    const float* w_out = (const float*)d_in[3];
    const float* b_out = (const float*)d_in[4];

    u16t* xb  = (u16t*)d_ws;
    u16t* wqt = xb  + (size_t)NTOK * EMBED;
    u16t* wot = wqt + (size_t)3072 * 1024;
    u16t* Qb  = wot + (size_t)1024 * 1024;
    u16t* Kb  = Qb  + (size_t)NTOK * EMBED;
    u16t* Vb  = Kb  + (size_t)NTOK * EMBED;
    u16t* Vtb = Vb  + (size_t)NTOK * EMBED;
    u16t* AOb = Vtb + (size_t)NTOK * EMBED;

    xcvt<<<2048, 256, 0, stream>>>(x, xb);
    wtrans<<<dim3(48, 16), 256, 0, stream>>>(w_qkv, wqt, 1024, 3072);
    wtrans<<<dim3(16, 16), 256, 0, stream>>>(w_out, wot, 1024, 1024);

    // QKV: 128x128 tiles, grid 24x32 = 768 blocks (nwg % 8 == 0)
    gemm_bf16<1, 4><<<dim3(24, 32), 256, 0, stream>>>(xb, wqt, b_qkv, 3072,
                                                      nullptr, Qb, Kb, Vb);
    vtrans<<<dim3(32, 32), 256, 0, stream>>>(Vb, Vtb);
    attn_mfma<<<dim3(16, 32), 256, 0, stream>>>(Qb, Kb, Vtb, AOb);
    // proj: 64x128 tiles, grid 8x64 = 512 blocks (nwg % 8 == 0)
    gemm_bf16<0, 2><<<dim3(8, 64), 256, 0, stream>>>(AOb, wot, b_out, 1024,
                                                     (float*)d_out, nullptr, nullptr, nullptr);
}